// Round 1
// baseline (242.281 us; speedup 1.0000x reference)
//
#include <hip/hip_runtime.h>

// dims: S=128, E=256 -> 32768 pairs; H=20, D=64, A=64, NH=8
constexpr float TEMP = 2.5f;    // H / sqrt(A) = 20/8
constexpr float NEGV = -1e9f;

// ---- workspace layout (floats) ----
constexpr int M_OFF = 0;        // M[8][64][64]  (pre-scaled by TEMP)
constexpr int K_OFF = 32768;    // k[8][64]
constexpr int P_OFF = 33280;    // p[8][64]
constexpr int Q_OFF = 33792;    // q[8]

// ---- main-kernel LDS layout (floats) ----
constexpr int HS_OFF  = 0;      // hs[8][20][65] padded   (10400)
constexpr int HT_OFF  = 10400;  // ht[8][68] padded       (544)
constexpr int V_OFF   = 10944;  // v/wv[8][516] (8 heads x 64 + pad) (4128)
constexpr int AT_OFF  = 15072;  // attn[8][20][20-stride] (3200)
constexpr int C_OFF   = 18272;  // c[8][8]                (64)
constexpr int LEN_OFF = 18336;  // len[8] as float        (8)
constexpr int LDS_FL  = 18344;  // 73,376 B -> 2 blocks/CU

// ============================================================
// prep: M[n][dp][d] = sum_a Wt[n][dp][a]*Ws[n][d][a];  k = Ws·bt;
//       p = Wt·bs;  q = bt·bs.  All scaled by TEMP.
// grid 32 = 8 heads x 4 dp-quarters, block 256.
// ============================================================
__global__ __launch_bounds__(256) void prep_kernel(
    const float* __restrict__ Wt, const float* __restrict__ bt,
    const float* __restrict__ Ws, const float* __restrict__ bs,
    float* __restrict__ ws) {
  __shared__ float WsL[64 * 65];
  __shared__ float WtL[16 * 65];
  const int t  = threadIdx.x;
  const int n  = blockIdx.x >> 2;
  const int q  = blockIdx.x & 3;
  const int dp0 = q * 16;
  const float* Wtn = Wt + n * 4096;
  const float* Wsn = Ws + n * 4096;
#pragma unroll
  for (int i = 0; i < 16; ++i) {
    const int idx = i * 256 + t;                 // 0..4095
    WsL[(idx >> 6) * 65 + (idx & 63)] = Wsn[idx];
  }
#pragma unroll
  for (int i = 0; i < 4; ++i) {
    const int idx = i * 256 + t;                 // 0..1023
    WtL[(idx >> 6) * 65 + (idx & 63)] = Wtn[dp0 * 64 + idx];
  }
  __syncthreads();
#pragma unroll
  for (int i = 0; i < 4; ++i) {
    const int idx = i * 256 + t;                 // 0..1023
    const int dpl = idx >> 6, d = idx & 63;
    const float* wtr = &WtL[dpl * 65];
    const float* wsr = &WsL[d * 65];
    float acc = 0.f;
#pragma unroll 8
    for (int a = 0; a < 64; ++a) acc += wtr[a] * wsr[a];
    ws[M_OFF + n * 4096 + (dp0 + dpl) * 64 + d] = acc * TEMP;
  }
  if (q == 0 && t < 64) {                        // k[n][d]
    float acc = 0.f;
#pragma unroll 8
    for (int a = 0; a < 64; ++a) acc += WsL[t * 65 + a] * bt[n * 64 + a];
    ws[K_OFF + n * 64 + t] = acc * TEMP;
  }
  if (t >= 64 && t < 80) {                       // p[n][dp0+r]
    const int r = t - 64;
    float acc = 0.f;
#pragma unroll 8
    for (int a = 0; a < 64; ++a) acc += WtL[r * 65 + a] * bs[n * 64 + a];
    ws[P_OFF + n * 64 + dp0 + r] = acc * TEMP;
  }
  if (q == 0 && t == 128) {                      // q[n]
    float acc = 0.f;
    for (int a = 0; a < 64; ++a) acc += bt[n * 64 + a] * bs[n * 64 + a];
    ws[Q_OFF + n] = acc * TEMP;
  }
}

// ============================================================
// main: 8 pairs per block, 256 threads (4 waves).
// ============================================================
__global__ __launch_bounds__(256) void attn_kernel(
    const float* __restrict__ ht_g, const float* __restrict__ hs_g,
    const int* __restrict__ len_g, const float* __restrict__ Wf,
    const float* __restrict__ bf, const float* __restrict__ wsp,
    float* __restrict__ out) {
  __shared__ float lds[LDS_FL];
  const int t    = threadIdx.x;
  const int lane = t & 63;
  const int w    = t >> 6;
  const int pair0 = blockIdx.x * 8;

  // ---------- P0: stage hs, ht, len ----------
  {
    const size_t hsbase = (size_t)pair0 * 1280;
#pragma unroll 4
    for (int i = 0; i < 40; ++i) {
      const int f = i * 256 + t;                 // 0..10239
      const int p = f / 1280;
      const int r = f - p * 1280;
      lds[HS_OFF + p * 1300 + (r >> 6) * 65 + (r & 63)] = hs_g[hsbase + f];
    }
#pragma unroll
    for (int i = 0; i < 2; ++i) {
      const int f = i * 256 + t;                 // 0..511
      lds[HT_OFF + (f >> 6) * 68 + (f & 63)] = ht_g[(size_t)pair0 * 64 + f];
    }
    if (t < 8) lds[LEN_OFF + t] = (float)len_g[pair0 + t];
  }
  __syncthreads();

  // ---------- P0b: c[p][n] = q[n] + ht·p[n]  (wave 0) ----------
  if (t < 64) {
    const int p = t >> 3, n = t & 7;
    const float* htp2 = &lds[HT_OFF + p * 68];
    float acc = wsp[Q_OFF + n];
#pragma unroll 4
    for (int dp = 0; dp < 64; ++dp) acc += htp2[dp] * wsp[P_OFF + n * 64 + dp];
    lds[C_OFF + t] = acc;
  }

  // ---------- P1: V[p][n][d] = k[n][d] + sum_dp ht[p][dp]*M[n][dp][d] ----------
  // wave w -> heads 2w,2w+1; lane = (pair p3, d-octet dq)
  {
    const int p3 = lane >> 3, dq = lane & 7;
    const float* htp = &lds[HT_OFF + p3 * 68];
    for (int nn = 0; nn < 2; ++nn) {
      const int n = (w << 1) + nn;
      float v[8];
      {
        const float4 k0 = *(const float4*)&wsp[K_OFF + n * 64 + dq * 8];
        const float4 k1 = *(const float4*)&wsp[K_OFF + n * 64 + dq * 8 + 4];
        v[0] = k0.x; v[1] = k0.y; v[2] = k0.z; v[3] = k0.w;
        v[4] = k1.x; v[5] = k1.y; v[6] = k1.z; v[7] = k1.w;
      }
      const float* Mrow = &wsp[M_OFF + n * 4096 + dq * 8];
#pragma unroll 4
      for (int dp = 0; dp < 64; ++dp) {
        const float hv = htp[dp];
        const float4 m0 = *(const float4*)(Mrow + dp * 64);
        const float4 m1 = *(const float4*)(Mrow + dp * 64 + 4);
        v[0] += hv * m0.x; v[1] += hv * m0.y; v[2] += hv * m0.z; v[3] += hv * m0.w;
        v[4] += hv * m1.x; v[5] += hv * m1.y; v[6] += hv * m1.z; v[7] += hv * m1.w;
      }
      float* vd = &lds[V_OFF + p3 * 516 + n * 64 + dq * 8];
      *(float4*)vd       = make_float4(v[0], v[1], v[2], v[3]);
      *(float4*)(vd + 4) = make_float4(v[4], v[5], v[6], v[7]);
    }
  }
  __syncthreads();

  // ---------- P2: scores (all heads folded into one hs pass) + softmax ----------
  // wave w -> pairs 2w,2w+1; lane = (pl, m) in 32-lane halves
  {
    const int pl = lane >> 5, m = lane & 31;
    const int p  = (w << 1) + pl;
    const int mm = (m < 20) ? m : 19;
    const float* hsrow = &lds[HS_OFF + p * 1300 + mm * 65];
    const float* vbase = &lds[V_OFF + p * 516];
    float s[8];
#pragma unroll
    for (int n = 0; n < 8; ++n) s[n] = lds[C_OFF + p * 8 + n];
#pragma unroll 2
    for (int dqi = 0; dqi < 16; ++dqi) {
      const float h0 = hsrow[dqi * 4 + 0];
      const float h1 = hsrow[dqi * 4 + 1];
      const float h2 = hsrow[dqi * 4 + 2];
      const float h3 = hsrow[dqi * 4 + 3];
#pragma unroll
      for (int n = 0; n < 8; ++n) {
        const float4 v4 = *(const float4*)&vbase[n * 64 + dqi * 4];
        s[n] += h0 * v4.x + h1 * v4.y + h2 * v4.z + h3 * v4.w;
      }
    }
    const int lenp = (int)lds[LEN_OFF + p];
    const bool act = (m < 20);
    float at[8];
#pragma unroll
    for (int n = 0; n < 8; ++n) {
      float sv = (act && m < lenp) ? s[n] : NEGV;   // scores pre-scaled by TEMP
      float mx = sv;
#pragma unroll
      for (int o = 16; o; o >>= 1) mx = fmaxf(mx, __shfl_xor(mx, o, 32));
      const float e = act ? __expf(sv - mx) : 0.f;
      float sm = e;
#pragma unroll
      for (int o = 16; o; o >>= 1) sm += __shfl_xor(sm, o, 32);
      at[n] = e / sm;
    }
    if (act) {
      float* dst = &lds[AT_OFF + p * 400 + m * 20];
      *(float4*)dst       = make_float4(at[0], at[1], at[2], at[3]);
      *(float4*)(dst + 4) = make_float4(at[4], at[5], at[6], at[7]);
    }
  }
  // no barrier needed: P3 touches only this wave's pairs

  // ---------- P3: wv[p][n][d] = sum_m attn[p][n][m]*hs[p][m][d]  (into V_l) ----------
  {
    const int d = lane;
#pragma unroll 2
    for (int pl = 0; pl < 2; ++pl) {
      const int p = (w << 1) + pl;
      float wv[8] = {0.f, 0.f, 0.f, 0.f, 0.f, 0.f, 0.f, 0.f};
      const float* hsp = &lds[HS_OFF + p * 1300];
      const float* atp = &lds[AT_OFF + p * 400];
#pragma unroll 4
      for (int m = 0; m < 20; ++m) {
        const float h = hsp[m * 65 + d];
        const float4 a0 = *(const float4*)&atp[m * 20];
        const float4 a1 = *(const float4*)&atp[m * 20 + 4];
        wv[0] += a0.x * h; wv[1] += a0.y * h; wv[2] += a0.z * h; wv[3] += a0.w * h;
        wv[4] += a1.x * h; wv[5] += a1.y * h; wv[6] += a1.z * h; wv[7] += a1.w * h;
      }
      float* vd = &lds[V_OFF + p * 516 + d];
#pragma unroll
      for (int n = 0; n < 8; ++n) vd[n * 64] = wv[n];
    }
  }
  __syncthreads();

  // ---------- P4a: y[p][n][d] = sum_dd wv[p][n][dd]*Wf[n*64+dd][d] ----------
  // wave w -> heads 2w,2w+1; y aliases the (dead) hs region.
  {
    const int d = lane;
    for (int nn = 0; nn < 2; ++nn) {
      const int n = (w << 1) + nn;
      float acc[8] = {0.f, 0.f, 0.f, 0.f, 0.f, 0.f, 0.f, 0.f};
      const float* wfb = &Wf[n * 4096 + d];
      const float* wvb = &lds[V_OFF + n * 64];
#pragma unroll 4
      for (int ddq = 0; ddq < 16; ++ddq) {
        const float wf0 = wfb[(ddq * 4 + 0) * 64];
        const float wf1 = wfb[(ddq * 4 + 1) * 64];
        const float wf2 = wfb[(ddq * 4 + 2) * 64];
        const float wf3 = wfb[(ddq * 4 + 3) * 64];
#pragma unroll
        for (int p = 0; p < 8; ++p) {
          const float4 v4 = *(const float4*)&wvb[p * 516 + ddq * 4];
          acc[p] += v4.x * wf0 + v4.y * wf1 + v4.z * wf2 + v4.w * wf3;
        }
      }
      float* yd = &lds[HS_OFF + n * 64 + d];
#pragma unroll
      for (int p = 0; p < 8; ++p) yd[p * 512] = acc[p];
    }
  }
  __syncthreads();

  // ---------- P4b: out[p][d] = bf[d] + sum_n y[p][n][d] ----------
#pragma unroll
  for (int i = 0; i < 2; ++i) {
    const int f = i * 256 + t;                   // 0..511
    const int p = f >> 6, d = f & 63;
    float acc = bf[d];
#pragma unroll
    for (int n = 0; n < 8; ++n) acc += lds[HS_OFF + p * 512 + n * 64 + d];
    out[(size_t)pair0 * 64 + f] = acc;
  }
}

extern "C" void kernel_launch(void* const* d_in, const int* in_sizes, int n_in,
                              void* d_out, int out_size, void* d_ws, size_t ws_size,
                              hipStream_t stream) {
  const float* ht  = (const float*)d_in[0];   // h_temporal [S,E,1,D]
  const float* hs  = (const float*)d_in[1];   // h_spatials [S,E,H,D]
  const int*   len = (const int*)d_in[2];     // each_seq_len [S*E]
  const float* Wt  = (const float*)d_in[3];   // [NH,D,A]
  const float* bt  = (const float*)d_in[4];   // [NH,A]
  const float* Ws  = (const float*)d_in[5];   // [NH,D,A]
  const float* bs  = (const float*)d_in[6];   // [NH,A]
  const float* Wf  = (const float*)d_in[7];   // [NH*D,D]
  const float* bf  = (const float*)d_in[8];   // [D]
  float* outp = (float*)d_out;
  float* ws   = (float*)d_ws;

  hipLaunchKernelGGL(prep_kernel, dim3(32), dim3(256), 0, stream,
                     Wt, bt, Ws, bs, ws);
  hipLaunchKernelGGL(attn_kernel, dim3(4096), dim3(256), 0, stream,
                     ht, hs, len, Wf, bf, ws, outp);
}